// Round 13
// baseline (136.234 us; speedup 1.0000x reference)
//
#include <hip/hip_runtime.h>
#include <math.h>

#define NQ 12
#define NTH 512
#define NL 3
#define GRID 768   // 3 blocks/CU x 256 CUs co-resident (LDS ~52KB)

typedef _Float16 h8 __attribute__((ext_vector_type(8)));
typedef _Float16 h4 __attribute__((ext_vector_type(4)));
typedef float f4 __attribute__((ext_vector_type(4)));

// R13 = R11 (3 blocks/CU, best: 84us dispatch) + dynamic pair-stealing via a
// global atomic counter in d_ws (R12 proved 2 blocks/CU loses more to barrier
// stalls than perfect balance gains; R11's residual was the 6-vs-5.33 iter
// tail). Next-pair grab + trig prefetch hide in existing barrier shadows:
// zero added barriers. Last-layer g2 barrier elided (R12-verified safe).

// suffix-xor = CNOT-chain permutation (R4/R7/R10-verified)
__device__ __forceinline__ int sfx(int v) {
    v ^= v >> 1; v ^= v >> 2; v ^= v >> 4; v ^= v >> 8;
    return v;
}
// State-buffer swizzle (R6-verified)
__device__ __forceinline__ int swzf(int off) {
    return off ^ (((((off >> 6) ^ (off >> 9)) & 7)) << 3);
}
// W-buffer swizzle (R7-verified)
__device__ __forceinline__ int swzw(int off) {
    return off ^ (((off >> 6) & 7) << 3);
}

// State layouts (R7/R10-verified): off = m*32 + reim*16 + tau
//   L0: tau=i[3:0],  m=i[11:4]
//   L1: tau=i[7:4],  m=i[9:8] | i[3:0]<<2 | i[11:10]<<6
//   L2: tau=i[11:8], m=i[7:0]

__global__ void __launch_bounds__(NTH)
qsim_kernel(const float* __restrict__ x,
            const float* __restrict__ params,
            const float* __restrict__ head_w,
            const float* __restrict__ head_b,
            float* __restrict__ out,
            int* __restrict__ counter, int Btot) {
    __shared__ __align__(16) _Float16 Sst[16384];  // 32 KB: states A | B(+8192)
    __shared__ __align__(16) _Float16 Wl[9216];    // 18 KB group matrices
    __shared__ float wlo[64], whi[64];             // R7-verified wsum LUTs
    __shared__ float csx[2 * 24], snx[2 * 24];     // trig, double-buffered pairs
    __shared__ float wred[16];
    __shared__ int npx[2];                         // stolen pair indices
    float* Gs = (float*)Sst;   // 288-float overlay, dead after W-build

    const int t = threadIdx.x;
    const int npairs = (Btot + 1) >> 1;

    // ---- Phase 1: disjoint lane ranges ----
    if (t == 0) npx[0] = atomicAdd(counter, 1);    // steal first pair
    if (t < 36) {   // fused 2x2 gates G = RY(p2)RZ(p1)RY(p0)  (R4-verified)
        float p0 = params[t * 3 + 0], p1 = params[t * 3 + 1], p2 = params[t * 3 + 2];
        float c0 = cosf(0.5f * p0), s0 = sinf(0.5f * p0);
        float ch = cosf(0.5f * p1), sh = sinf(0.5f * p1);
        float c2 = cosf(0.5f * p2), s2 = sinf(0.5f * p2);
        float pr = ch, pi = -sh, qr = ch, qi = sh;
        float A = c2 * c0, Bc = s2 * s0, Cc = c2 * s0, D = s2 * c0;
        float* g = &Gs[t * 8];
        g[0] = A * pr - Bc * qr;  g[1] = A * pi - Bc * qi;
        g[2] = -Cc * pr - D * qr; g[3] = -Cc * pi - D * qi;
        g[4] = D * pr + Cc * qr;  g[5] = D * pi + Cc * qi;
        g[6] = -Bc * pr + A * qr; g[7] = -Bc * pi + A * qi;
    }
    if (t >= 64 && t < 128) {      // wlo: bits 0..5 <-> wires 11..6
        int v = t - 64; float s = 0.f;
#pragma unroll
        for (int be = 0; be < 6; ++be)
            s += ((v >> be) & 1) ? -head_w[11 - be] : head_w[11 - be];
        wlo[v] = s;
    }
    if (t >= 128 && t < 192) {     // whi: bits 0..5 <-> wires 5..0
        int v = t - 128; float s = 0.f;
#pragma unroll
        for (int be = 0; be < 6; ++be)
            s += ((v >> be) & 1) ? -head_w[5 - be] : head_w[5 - be];
        whi[v] = s;
    }
    __syncthreads();

    // trig for the first stolen pair (buf 0); npx[0] ordered by barrier above
    if (t >= 64 && t < 88) {
        int idx = t - 64;
        int p0i = npx[0];
        if (p0i < npairs) {
            int smp = p0i * 2 + (idx >= 12 ? 1 : 0);
            int wire = (idx >= 12) ? (idx - 12) : idx;
            if (smp < Btot) {
                float xv = 0.5f * x[smp * NQ + wire];
                csx[idx] = cosf(xv);
                snx[idx] = sinf(xv);
            }
        }
    }

    // ---- Phase 2: W build, VERBATIM R10 (once per block) ----
#pragma unroll
    for (int i = 0; i < 18; ++i) {
        int e = i * 512 + t;
        int s = e >> 10, idx = e & 1023;
        int n = idx >> 5, k = idx & 31;
        int rp = n >> 4, tp = n & 15, rr = k >> 4, tt = k & 15;
        int l = s / 3, g = s - 3 * l;
        float ur = 1.f, ui = 0.f;
#pragma unroll
        for (int jj = 0; jj < 4; ++jj) {
            int wire = 11 - (4 * g + jj);
            const float* gp = &Gs[(l * 12 + wire) * 8];
            int rb = (tp >> jj) & 1, cb = (tt >> jj) & 1;
            float gr = gp[(rb * 2 + cb) * 2], gi = gp[(rb * 2 + cb) * 2 + 1];
            float nr = ur * gr - ui * gi;
            float ni = ur * gi + ui * gr;
            ur = nr; ui = ni;
        }
        float val = (rp == 0) ? ((rr == 0) ? ur : -ui)
                              : ((rr == 0) ? ui : ur);
        Wl[swzw(e)] = (_Float16)val;
    }
    __syncthreads();

    // ---- per-lane constants (VERBATIM R11) ----
    const int u = t & 15, q = (t >> 4) & 3, wv = t >> 6;
    const int abase0 = swzf((wv * 16 + u) * 32 + q * 8);
    const int abase1 = swzf(((wv + 8) * 16 + u) * 32 + q * 8);
    const int wbs = swzw(u * 32 + q * 8);
    const int wv3 = wv & 3, wvh = wv >> 2;
    const int mf0 = (wv3 | (u << 2) | (wvh << 6)) * 32;
    const int mf1 = (wv3 | (u << 2) | ((wvh + 2) << 6)) * 32;
    const int s00 = swzf(mf0 + q * 4), s01 = swzf(mf0 + 16 + q * 4);
    const int s10 = swzf(mf1 + q * 4), s11 = swzf(mf1 + 16 + q * 4);
    const int p4 = (wv * 4 + q) & 15;
    const int bm = (p4 | (u << 4)) * 32 + (wv >> 2) * 4;
    const int b00 = swzf(bm), b01 = swzf(bm + 16), b10 = swzf(bm + 8), b11 = swzf(bm + 24);
    const int j0a = sfx(u * 256 + wv * 16 + q * 4);
    const int j0b = sfx(u * 256 + (wv + 8) * 16 + q * 4);
    const int cca = j0a & 3, ccb = j0b & 3;
    const int ea = cca ^ (cca >> 1), eb = ccb ^ (ccb >> 1);
    const int jba = j0a ^ cca, jbb = j0b ^ ccb;
    const int obA = ((jba >> 4) << 5) | (jba & 12);
    const int obB = ((jbb >> 4) << 5) | (jbb & 12);
    const int pA0 = swzf(obA), pA1 = swzf(obA + 16);
    const int pB0 = swzf(obB), pB1 = swzf(obB + 16);
    const float wha = whi[j0a >> 6], whb = whi[j0b >> 6];
    const int jla = j0a & 63, jlb = j0b & 63;
    const float W0a = wlo[jla] + wha, W1a = wlo[jla ^ 1] + wha;
    const float W2a = wlo[jla ^ 3] + wha, W3a = wlo[jla ^ 2] + wha;
    const float W0b = wlo[jlb] + whb, W1b = wlo[jlb ^ 1] + whb;
    const float W2b = wlo[jlb ^ 3] + whb, W3b = wlo[jlb ^ 2] + whb;
    const f4 Z = {0.f, 0.f, 0.f, 0.f};

#define STH(off_, c_) { h4 w_;                                               \
    w_.x = (_Float16)(c_).x; w_.y = (_Float16)(c_).y;                        \
    w_.z = (_Float16)(c_).z; w_.w = (_Float16)(c_).w;                        \
    *(h4*)&Sst[off_] = w_; }

#define PSTH(off_, SOFF_, e_, v_) {                                          \
    bool e1_ = ((e_) & 1), e2_ = (((e_) & 2) != 0);                          \
    float b0_ = e1_ ? (v_).y : (v_).x, b1_ = e1_ ? (v_).x : (v_).y;          \
    float b2_ = e1_ ? (v_).w : (v_).z, b3_ = e1_ ? (v_).z : (v_).w;          \
    h4 w_;                                                                   \
    w_.x = (_Float16)(e2_ ? b2_ : b0_); w_.y = (_Float16)(e2_ ? b3_ : b1_);  \
    w_.z = (_Float16)(e2_ ? b1_ : b3_); w_.w = (_Float16)(e2_ ? b0_ : b2_);  \
    *(h4*)&Sst[(off_) + (SOFF_)] = w_; }

// reads + 8 MFMAs, NO trailing barrier
#define KSTEP_NB(sW_) {                                                      \
    h8 bf0 = *(const h8*)&Wl[(sW_) + wbs];                                   \
    h8 bf1 = *(const h8*)&Wl[(sW_) + 512 + wbs];                             \
    h8 a0A = *(const h8*)&Sst[abase0];                                       \
    h8 a1A = *(const h8*)&Sst[abase1];                                       \
    h8 a0B = *(const h8*)&Sst[abase0 + 8192];                                \
    h8 a1B = *(const h8*)&Sst[abase1 + 8192];                                \
    cA00 = __builtin_amdgcn_mfma_f32_16x16x32_f16(a0A, bf0, Z, 0, 0, 0);     \
    cA01 = __builtin_amdgcn_mfma_f32_16x16x32_f16(a0A, bf1, Z, 0, 0, 0);     \
    cA10 = __builtin_amdgcn_mfma_f32_16x16x32_f16(a1A, bf0, Z, 0, 0, 0);     \
    cA11 = __builtin_amdgcn_mfma_f32_16x16x32_f16(a1A, bf1, Z, 0, 0, 0);     \
    cB00 = __builtin_amdgcn_mfma_f32_16x16x32_f16(a0B, bf0, Z, 0, 0, 0);     \
    cB01 = __builtin_amdgcn_mfma_f32_16x16x32_f16(a0B, bf1, Z, 0, 0, 0);     \
    cB10 = __builtin_amdgcn_mfma_f32_16x16x32_f16(a1B, bf0, Z, 0, 0, 0);     \
    cB11 = __builtin_amdgcn_mfma_f32_16x16x32_f16(a1B, bf1, Z, 0, 0, 0);     \
}

#define KSTEP(sW_) { KSTEP_NB(sW_) __syncthreads(); }

#define INITS(cs_, sn_, SOFF_) {                                             \
    int m_ = t & 255, reim_ = t >> 8;                                        \
    float magm_ = 1.f;                                                       \
    _Pragma("unroll") for (int j_ = 0; j_ < 8; ++j_)                         \
        magm_ *= ((m_ >> j_) & 1) ? (sn_)[7 - j_] : (cs_)[7 - j_];           \
    float A2_[4], B2_[4];                                                    \
    _Pragma("unroll") for (int v_ = 0; v_ < 4; ++v_) {                       \
        A2_[v_] = ((v_ & 1) ? (sn_)[11] : (cs_)[11]) *                       \
                  ((v_ & 2) ? (sn_)[10] : (cs_)[10]);                        \
        B2_[v_] = ((v_ & 1) ? (sn_)[9] : (cs_)[9]) *                         \
                  ((v_ & 2) ? (sn_)[8] : (cs_)[8]);                          \
    }                                                                        \
    int pm_ = __popc(m_);                                                    \
    h8 w0_, w1_;                                                             \
    _Pragma("unroll") for (int tau_ = 0; tau_ < 16; ++tau_) {                \
        float mag_ = magm_ * A2_[tau_ & 3] * B2_[tau_ >> 2];                 \
        int p_ = (pm_ + __popc(tau_)) & 3;                                   \
        bool nz_ = ((p_ & 1) == reim_);                                      \
        bool ng_ = ((((p_ >> 1) & 1) ^ reim_) != 0);                         \
        float v_ = nz_ ? (ng_ ? -mag_ : mag_) : 0.f;                         \
        if (tau_ < 8) w0_[tau_] = (_Float16)v_; else w1_[tau_ - 8] = (_Float16)v_; \
    }                                                                        \
    int off_ = m_ * 32 + reim_ * 16;                                         \
    *(h8*)&Sst[swzf(off_) + (SOFF_)] = w0_;                                  \
    *(h8*)&Sst[swzf(off_ + 8) + (SOFF_)] = w1_; }

    // ---- dynamic pair loop ----
    int c = 0;
#pragma unroll 1
    for (;;) {
        const int pairIdx = npx[c];
        if (pairIdx >= npairs) break;
        const float* cs0 = &csx[c * 24];
        const float* sn0 = &snx[c * 24];
        INITS(cs0, sn0, 0)
        INITS((cs0 + 12), (sn0 + 12), 8192)
        if (t == 0) npx[c ^ 1] = atomicAdd(counter, 1);   // steal next pair
        __syncthreads();

        float racc0 = 0.f, racc1 = 0.f;
#pragma unroll
        for (int l = 0; l < NL; ++l) {
            f4 cA00, cA01, cA10, cA11, cB00, cB01, cB10, cB11;
            // ---- g=0: wires 8..11 ----
            KSTEP((l * 3 + 0) * 1024)
            STH(s00, cA00) STH(s01, cA01) STH(s10, cA10) STH(s11, cA11)
            STH(s00 + 8192, cB00) STH(s01 + 8192, cB01)
            STH(s10 + 8192, cB10) STH(s11 + 8192, cB11)
            __syncthreads();
            if (l == 0 && t >= 64 && t < 88) {   // trig prefetch for next pair
                int idx = t - 64;                // (npx write ordered by INIT
                int p2i = npx[c ^ 1];            //  barrier; csx[c^1] read next
                if (p2i < npairs) {              //  iter after wred barrier)
                    int smp = p2i * 2 + (idx >= 12 ? 1 : 0);
                    int wire = (idx >= 12) ? (idx - 12) : idx;
                    if (smp < Btot) {
                        float xv = 0.5f * x[smp * NQ + wire];
                        csx[(c ^ 1) * 24 + idx] = cosf(xv);
                        snx[(c ^ 1) * 24 + idx] = sinf(xv);
                    }
                }
            }
            // ---- g=1: wires 4..7 ----
            KSTEP((l * 3 + 1) * 1024)
            STH(b00, cA00) STH(b01, cA01) STH(b10, cA10) STH(b11, cA11)
            STH(b00 + 8192, cB00) STH(b01 + 8192, cB01)
            STH(b10 + 8192, cB10) STH(b11 + 8192, cB11)
            __syncthreads();
            // ---- g=2: wires 0..3 ----
            if (l < NL - 1) {
                KSTEP((l * 3 + 2) * 1024)
                PSTH(pA0, 0, ea, cA00) PSTH(pA1, 0, ea, cA01)
                PSTH(pB0, 0, eb, cA10) PSTH(pB1, 0, eb, cA11)
                PSTH(pA0, 8192, ea, cB00) PSTH(pA1, 8192, ea, cB01)
                PSTH(pB0, 8192, eb, cB10) PSTH(pB1, 8192, eb, cB11)
                __syncthreads();
            } else {
                // last g2: barrier elided (R12-verified safe: next Sst write
                // is next iter's INIT, ordered behind the wred barrier)
                KSTEP_NB((l * 3 + 2) * 1024)
                racc0 = fmaf(fmaf(cA00.x, cA00.x, cA01.x * cA01.x), W0a, racc0);
                racc0 = fmaf(fmaf(cA00.y, cA00.y, cA01.y * cA01.y), W1a, racc0);
                racc0 = fmaf(fmaf(cA00.z, cA00.z, cA01.z * cA01.z), W2a, racc0);
                racc0 = fmaf(fmaf(cA00.w, cA00.w, cA01.w * cA01.w), W3a, racc0);
                racc0 = fmaf(fmaf(cA10.x, cA10.x, cA11.x * cA11.x), W0b, racc0);
                racc0 = fmaf(fmaf(cA10.y, cA10.y, cA11.y * cA11.y), W1b, racc0);
                racc0 = fmaf(fmaf(cA10.z, cA10.z, cA11.z * cA11.z), W2b, racc0);
                racc0 = fmaf(fmaf(cA10.w, cA10.w, cA11.w * cA11.w), W3b, racc0);
                racc1 = fmaf(fmaf(cB00.x, cB00.x, cB01.x * cB01.x), W0a, racc1);
                racc1 = fmaf(fmaf(cB00.y, cB00.y, cB01.y * cB01.y), W1a, racc1);
                racc1 = fmaf(fmaf(cB00.z, cB00.z, cB01.z * cB01.z), W2a, racc1);
                racc1 = fmaf(fmaf(cB00.w, cB00.w, cB01.w * cB01.w), W3a, racc1);
                racc1 = fmaf(fmaf(cB10.x, cB10.x, cB11.x * cB11.x), W0b, racc1);
                racc1 = fmaf(fmaf(cB10.y, cB10.y, cB11.y * cB11.y), W1b, racc1);
                racc1 = fmaf(fmaf(cB10.z, cB10.z, cB11.z * cB11.z), W2b, racc1);
                racc1 = fmaf(fmaf(cB10.w, cB10.w, cB11.w * cB11.w), W3b, racc1);
            }
        }
#pragma unroll
        for (int o = 32; o >= 1; o >>= 1) {
            racc0 += __shfl_xor(racc0, o, 64);
            racc1 += __shfl_xor(racc1, o, 64);
        }
        if ((t & 63) == 0) { wred[wv] = racc0; wred[8 + wv] = racc1; }
        __syncthreads();
        if (t < 2) {
            int smp = pairIdx * 2 + t;
            if (smp < Btot) {
                float r = head_b[0];
#pragma unroll
                for (int i2 = 0; i2 < 8; ++i2) r += wred[t * 8 + i2];
                out[smp] = r;
            }
        }
        c ^= 1;
    }
}

extern "C" void kernel_launch(void* const* d_in, const int* in_sizes, int n_in,
                              void* d_out, int out_size, void* d_ws, size_t ws_size,
                              hipStream_t stream) {
    const float* x = (const float*)d_in[0];
    const float* params = (const float*)d_in[1];
    const float* head_w = (const float*)d_in[2];
    const float* head_b = (const float*)d_in[3];
    float* out = (float*)d_out;
    int* counter = (int*)d_ws;
    int B = in_sizes[0] / NQ;

    // zero the work-stealing counter (d_ws is re-poisoned 0xAA each call);
    // hipMemsetAsync is graph-capturable (memset node)
    hipMemsetAsync(counter, 0, sizeof(int), stream);
    hipLaunchKernelGGL(qsim_kernel, dim3(GRID), dim3(NTH), 0, stream,
                       x, params, head_w, head_b, out, counter, B);
}

// Round 14
// 127.663 us; speedup vs baseline: 1.0671x; 1.0671x over previous
//
#include <hip/hip_runtime.h>
#include <math.h>

#define NQ 12
#define NTH 512
#define NL 3
#define GRID 768   // 3 blocks/CU x 256 CUs; grid-stride over pairs (R11-best)

typedef _Float16 h8 __attribute__((ext_vector_type(8)));
typedef _Float16 h4 __attribute__((ext_vector_type(4)));
typedef float f4 __attribute__((ext_vector_type(4)));

// R14 = R11 VERBATIM (best: 84us dispatch / 127.7us total) + the one
// R12/R13-correctness-verified micro-win: last-layer g2 barrier elided.
// R12 (2 blocks/CU static balance) and R13 (atomic work-stealing) both
// REGRESSED vs R11 -> balance was not the residual; DS-pipe ~82% + barrier
// latency is the structural floor of this decomposition.

// suffix-xor = CNOT-chain permutation (R4/R7/R10-verified)
__device__ __forceinline__ int sfx(int v) {
    v ^= v >> 1; v ^= v >> 2; v ^= v >> 4; v ^= v >> 8;
    return v;
}
// State-buffer swizzle (R6-verified)
__device__ __forceinline__ int swzf(int off) {
    return off ^ (((((off >> 6) ^ (off >> 9)) & 7)) << 3);
}
// W-buffer swizzle (R7-verified)
__device__ __forceinline__ int swzw(int off) {
    return off ^ (((off >> 6) & 7) << 3);
}

// State layouts (R7/R10-verified): off = m*32 + reim*16 + tau
//   L0: tau=i[3:0],  m=i[11:4]
//   L1: tau=i[7:4],  m=i[9:8] | i[3:0]<<2 | i[11:10]<<6
//   L2: tau=i[11:8], m=i[7:0]

__global__ void __launch_bounds__(NTH)
qsim_kernel(const float* __restrict__ x,
            const float* __restrict__ params,
            const float* __restrict__ head_w,
            const float* __restrict__ head_b,
            float* __restrict__ out, int Btot) {
    __shared__ __align__(16) _Float16 Sst[16384];  // 32 KB: states A | B(+8192)
    __shared__ __align__(16) _Float16 Wl[9216];    // 18 KB group matrices
    __shared__ float wlo[64], whi[64];             // R7-verified wsum LUTs
    __shared__ float csx[6 * 24], snx[6 * 24];     // trig for up to 6 pairs
    __shared__ float wred[16];
    float* Gs = (float*)Sst;   // 288-float overlay, dead after W-build

    const int t = threadIdx.x, blk = blockIdx.x;
    const int npairs = (Btot + 1) >> 1;

    // ---- Phase 1: disjoint lane ranges ----
    if (t < 36) {   // fused 2x2 gates G = RY(p2)RZ(p1)RY(p0)  (R4-verified)
        float p0 = params[t * 3 + 0], p1 = params[t * 3 + 1], p2 = params[t * 3 + 2];
        float c0 = cosf(0.5f * p0), s0 = sinf(0.5f * p0);
        float ch = cosf(0.5f * p1), sh = sinf(0.5f * p1);
        float c2 = cosf(0.5f * p2), s2 = sinf(0.5f * p2);
        float pr = ch, pi = -sh, qr = ch, qi = sh;
        float A = c2 * c0, Bc = s2 * s0, Cc = c2 * s0, D = s2 * c0;
        float* g = &Gs[t * 8];
        g[0] = A * pr - Bc * qr;  g[1] = A * pi - Bc * qi;
        g[2] = -Cc * pr - D * qr; g[3] = -Cc * pi - D * qi;
        g[4] = D * pr + Cc * qr;  g[5] = D * pi + Cc * qi;
        g[6] = -Bc * pr + A * qr; g[7] = -Bc * pi + A * qi;
    }
    if (t >= 64 && t < 208) {      // RX trig for this block's <=6 pairs
        int idx = t - 64;
        int pr = idx / 24, w = idx - pr * 24;
        int pairIdx = blk + pr * GRID;
        if (pairIdx < npairs) {
            int smp = pairIdx * 2 + (w >= 12 ? 1 : 0);
            int wire = (w >= 12) ? (w - 12) : w;
            if (smp < Btot) {
                float xv = 0.5f * x[smp * NQ + wire];
                csx[pr * 24 + w] = cosf(xv);
                snx[pr * 24 + w] = sinf(xv);
            }
        }
    }
    if (t >= 256 && t < 320) {     // wlo: bits 0..5 <-> wires 11..6
        int v = t - 256; float s = 0.f;
#pragma unroll
        for (int be = 0; be < 6; ++be)
            s += ((v >> be) & 1) ? -head_w[11 - be] : head_w[11 - be];
        wlo[v] = s;
    }
    if (t >= 320 && t < 384) {     // whi: bits 0..5 <-> wires 5..0
        int v = t - 320; float s = 0.f;
#pragma unroll
        for (int be = 0; be < 6; ++be)
            s += ((v >> be) & 1) ? -head_w[5 - be] : head_w[5 - be];
        whi[v] = s;
    }
    __syncthreads();

    // ---- Phase 2: W build, VERBATIM R10 (once per block) ----
#pragma unroll
    for (int i = 0; i < 18; ++i) {
        int e = i * 512 + t;
        int s = e >> 10, idx = e & 1023;
        int n = idx >> 5, k = idx & 31;
        int rp = n >> 4, tp = n & 15, rr = k >> 4, tt = k & 15;
        int l = s / 3, g = s - 3 * l;
        float ur = 1.f, ui = 0.f;
#pragma unroll
        for (int jj = 0; jj < 4; ++jj) {
            int wire = 11 - (4 * g + jj);
            const float* gp = &Gs[(l * 12 + wire) * 8];
            int rb = (tp >> jj) & 1, cb = (tt >> jj) & 1;
            float gr = gp[(rb * 2 + cb) * 2], gi = gp[(rb * 2 + cb) * 2 + 1];
            float nr = ur * gr - ui * gi;
            float ni = ur * gi + ui * gr;
            ur = nr; ui = ni;
        }
        float val = (rp == 0) ? ((rr == 0) ? ur : -ui)
                              : ((rr == 0) ? ui : ur);
        Wl[swzw(e)] = (_Float16)val;
    }
    __syncthreads();

    // ---- per-lane constants (VERBATIM R11) ----
    const int u = t & 15, q = (t >> 4) & 3, wv = t >> 6;
    const int abase0 = swzf((wv * 16 + u) * 32 + q * 8);
    const int abase1 = swzf(((wv + 8) * 16 + u) * 32 + q * 8);
    const int wbs = swzw(u * 32 + q * 8);
    const int wv3 = wv & 3, wvh = wv >> 2;
    const int mf0 = (wv3 | (u << 2) | (wvh << 6)) * 32;
    const int mf1 = (wv3 | (u << 2) | ((wvh + 2) << 6)) * 32;
    const int s00 = swzf(mf0 + q * 4), s01 = swzf(mf0 + 16 + q * 4);
    const int s10 = swzf(mf1 + q * 4), s11 = swzf(mf1 + 16 + q * 4);
    const int p4 = (wv * 4 + q) & 15;
    const int bm = (p4 | (u << 4)) * 32 + (wv >> 2) * 4;
    const int b00 = swzf(bm), b01 = swzf(bm + 16), b10 = swzf(bm + 8), b11 = swzf(bm + 24);
    const int j0a = sfx(u * 256 + wv * 16 + q * 4);
    const int j0b = sfx(u * 256 + (wv + 8) * 16 + q * 4);
    const int cca = j0a & 3, ccb = j0b & 3;
    const int ea = cca ^ (cca >> 1), eb = ccb ^ (ccb >> 1);
    const int jba = j0a ^ cca, jbb = j0b ^ ccb;
    const int obA = ((jba >> 4) << 5) | (jba & 12);
    const int obB = ((jbb >> 4) << 5) | (jbb & 12);
    const int pA0 = swzf(obA), pA1 = swzf(obA + 16);
    const int pB0 = swzf(obB), pB1 = swzf(obB + 16);
    const float wha = whi[j0a >> 6], whb = whi[j0b >> 6];
    const int jla = j0a & 63, jlb = j0b & 63;
    const float W0a = wlo[jla] + wha, W1a = wlo[jla ^ 1] + wha;
    const float W2a = wlo[jla ^ 3] + wha, W3a = wlo[jla ^ 2] + wha;
    const float W0b = wlo[jlb] + whb, W1b = wlo[jlb ^ 1] + whb;
    const float W2b = wlo[jlb ^ 3] + whb, W3b = wlo[jlb ^ 2] + whb;
    const f4 Z = {0.f, 0.f, 0.f, 0.f};

#define STH(off_, c_) { h4 w_;                                               \
    w_.x = (_Float16)(c_).x; w_.y = (_Float16)(c_).y;                        \
    w_.z = (_Float16)(c_).z; w_.w = (_Float16)(c_).w;                        \
    *(h4*)&Sst[off_] = w_; }

#define PSTH(off_, SOFF_, e_, v_) {                                          \
    bool e1_ = ((e_) & 1), e2_ = (((e_) & 2) != 0);                          \
    float b0_ = e1_ ? (v_).y : (v_).x, b1_ = e1_ ? (v_).x : (v_).y;          \
    float b2_ = e1_ ? (v_).w : (v_).z, b3_ = e1_ ? (v_).z : (v_).w;          \
    h4 w_;                                                                   \
    w_.x = (_Float16)(e2_ ? b2_ : b0_); w_.y = (_Float16)(e2_ ? b3_ : b1_);  \
    w_.z = (_Float16)(e2_ ? b1_ : b3_); w_.w = (_Float16)(e2_ ? b0_ : b2_);  \
    *(h4*)&Sst[(off_) + (SOFF_)] = w_; }

// reads + 8 MFMAs, NO trailing barrier
#define KSTEP_NB(sW_) {                                                      \
    h8 bf0 = *(const h8*)&Wl[(sW_) + wbs];                                   \
    h8 bf1 = *(const h8*)&Wl[(sW_) + 512 + wbs];                             \
    h8 a0A = *(const h8*)&Sst[abase0];                                       \
    h8 a1A = *(const h8*)&Sst[abase1];                                       \
    h8 a0B = *(const h8*)&Sst[abase0 + 8192];                                \
    h8 a1B = *(const h8*)&Sst[abase1 + 8192];                                \
    cA00 = __builtin_amdgcn_mfma_f32_16x16x32_f16(a0A, bf0, Z, 0, 0, 0);     \
    cA01 = __builtin_amdgcn_mfma_f32_16x16x32_f16(a0A, bf1, Z, 0, 0, 0);     \
    cA10 = __builtin_amdgcn_mfma_f32_16x16x32_f16(a1A, bf0, Z, 0, 0, 0);     \
    cA11 = __builtin_amdgcn_mfma_f32_16x16x32_f16(a1A, bf1, Z, 0, 0, 0);     \
    cB00 = __builtin_amdgcn_mfma_f32_16x16x32_f16(a0B, bf0, Z, 0, 0, 0);     \
    cB01 = __builtin_amdgcn_mfma_f32_16x16x32_f16(a0B, bf1, Z, 0, 0, 0);     \
    cB10 = __builtin_amdgcn_mfma_f32_16x16x32_f16(a1B, bf0, Z, 0, 0, 0);     \
    cB11 = __builtin_amdgcn_mfma_f32_16x16x32_f16(a1B, bf1, Z, 0, 0, 0);     \
}

#define KSTEP(sW_) { KSTEP_NB(sW_) __syncthreads(); }

#define INITS(cs_, sn_, SOFF_) {                                             \
    int m_ = t & 255, reim_ = t >> 8;                                        \
    float magm_ = 1.f;                                                       \
    _Pragma("unroll") for (int j_ = 0; j_ < 8; ++j_)                         \
        magm_ *= ((m_ >> j_) & 1) ? (sn_)[7 - j_] : (cs_)[7 - j_];           \
    float A2_[4], B2_[4];                                                    \
    _Pragma("unroll") for (int v_ = 0; v_ < 4; ++v_) {                       \
        A2_[v_] = ((v_ & 1) ? (sn_)[11] : (cs_)[11]) *                       \
                  ((v_ & 2) ? (sn_)[10] : (cs_)[10]);                        \
        B2_[v_] = ((v_ & 1) ? (sn_)[9] : (cs_)[9]) *                         \
                  ((v_ & 2) ? (sn_)[8] : (cs_)[8]);                          \
    }                                                                        \
    int pm_ = __popc(m_);                                                    \
    h8 w0_, w1_;                                                             \
    _Pragma("unroll") for (int tau_ = 0; tau_ < 16; ++tau_) {                \
        float mag_ = magm_ * A2_[tau_ & 3] * B2_[tau_ >> 2];                 \
        int p_ = (pm_ + __popc(tau_)) & 3;                                   \
        bool nz_ = ((p_ & 1) == reim_);                                      \
        bool ng_ = ((((p_ >> 1) & 1) ^ reim_) != 0);                         \
        float v_ = nz_ ? (ng_ ? -mag_ : mag_) : 0.f;                         \
        if (tau_ < 8) w0_[tau_] = (_Float16)v_; else w1_[tau_ - 8] = (_Float16)v_; \
    }                                                                        \
    int off_ = m_ * 32 + reim_ * 16;                                         \
    *(h8*)&Sst[swzf(off_) + (SOFF_)] = w0_;                                  \
    *(h8*)&Sst[swzf(off_ + 8) + (SOFF_)] = w1_; }

    // ---- pair loop (grid-stride over 4096 pairs) ----
#pragma unroll 1
    for (int pr = 0; ; ++pr) {
        const int pairIdx = blk + pr * GRID;
        if (pairIdx >= npairs) break;
        const float* cs0 = &csx[pr * 24];
        const float* sn0 = &snx[pr * 24];
        INITS(cs0, sn0, 0)
        INITS((cs0 + 12), (sn0 + 12), 8192)
        __syncthreads();

        float racc0 = 0.f, racc1 = 0.f;
#pragma unroll
        for (int l = 0; l < NL; ++l) {
            f4 cA00, cA01, cA10, cA11, cB00, cB01, cB10, cB11;
            // ---- g=0: wires 8..11 ----
            KSTEP((l * 3 + 0) * 1024)
            STH(s00, cA00) STH(s01, cA01) STH(s10, cA10) STH(s11, cA11)
            STH(s00 + 8192, cB00) STH(s01 + 8192, cB01)
            STH(s10 + 8192, cB10) STH(s11 + 8192, cB11)
            __syncthreads();
            // ---- g=1: wires 4..7 ----
            KSTEP((l * 3 + 1) * 1024)
            STH(b00, cA00) STH(b01, cA01) STH(b10, cA10) STH(b11, cA11)
            STH(b00 + 8192, cB00) STH(b01 + 8192, cB01)
            STH(b10 + 8192, cB10) STH(b11 + 8192, cB11)
            __syncthreads();
            // ---- g=2: wires 0..3 ----
            if (l < NL - 1) {
                KSTEP((l * 3 + 2) * 1024)
                PSTH(pA0, 0, ea, cA00) PSTH(pA1, 0, ea, cA01)
                PSTH(pB0, 0, eb, cA10) PSTH(pB1, 0, eb, cA11)
                PSTH(pA0, 8192, ea, cB00) PSTH(pA1, 8192, ea, cB01)
                PSTH(pB0, 8192, eb, cB10) PSTH(pB1, 8192, eb, cB11)
                __syncthreads();
            } else {
                // last g2: barrier elided (R12/R13-verified safe: next Sst
                // write is next iter's INIT, ordered behind the wred barrier)
                KSTEP_NB((l * 3 + 2) * 1024)
                racc0 = fmaf(fmaf(cA00.x, cA00.x, cA01.x * cA01.x), W0a, racc0);
                racc0 = fmaf(fmaf(cA00.y, cA00.y, cA01.y * cA01.y), W1a, racc0);
                racc0 = fmaf(fmaf(cA00.z, cA00.z, cA01.z * cA01.z), W2a, racc0);
                racc0 = fmaf(fmaf(cA00.w, cA00.w, cA01.w * cA01.w), W3a, racc0);
                racc0 = fmaf(fmaf(cA10.x, cA10.x, cA11.x * cA11.x), W0b, racc0);
                racc0 = fmaf(fmaf(cA10.y, cA10.y, cA11.y * cA11.y), W1b, racc0);
                racc0 = fmaf(fmaf(cA10.z, cA10.z, cA11.z * cA11.z), W2b, racc0);
                racc0 = fmaf(fmaf(cA10.w, cA10.w, cA11.w * cA11.w), W3b, racc0);
                racc1 = fmaf(fmaf(cB00.x, cB00.x, cB01.x * cB01.x), W0a, racc1);
                racc1 = fmaf(fmaf(cB00.y, cB00.y, cB01.y * cB01.y), W1a, racc1);
                racc1 = fmaf(fmaf(cB00.z, cB00.z, cB01.z * cB01.z), W2a, racc1);
                racc1 = fmaf(fmaf(cB00.w, cB00.w, cB01.w * cB01.w), W3a, racc1);
                racc1 = fmaf(fmaf(cB10.x, cB10.x, cB11.x * cB11.x), W0b, racc1);
                racc1 = fmaf(fmaf(cB10.y, cB10.y, cB11.y * cB11.y), W1b, racc1);
                racc1 = fmaf(fmaf(cB10.z, cB10.z, cB11.z * cB11.z), W2b, racc1);
                racc1 = fmaf(fmaf(cB10.w, cB10.w, cB11.w * cB11.w), W3b, racc1);
            }
        }
#pragma unroll
        for (int o = 32; o >= 1; o >>= 1) {
            racc0 += __shfl_xor(racc0, o, 64);
            racc1 += __shfl_xor(racc1, o, 64);
        }
        if ((t & 63) == 0) { wred[wv] = racc0; wred[8 + wv] = racc1; }
        __syncthreads();
        if (t < 2) {
            int smp = pairIdx * 2 + t;
            if (smp < Btot) {
                float r = head_b[0];
#pragma unroll
                for (int i2 = 0; i2 < 8; ++i2) r += wred[t * 8 + i2];
                out[smp] = r;
            }
        }
    }
}

extern "C" void kernel_launch(void* const* d_in, const int* in_sizes, int n_in,
                              void* d_out, int out_size, void* d_ws, size_t ws_size,
                              hipStream_t stream) {
    const float* x = (const float*)d_in[0];
    const float* params = (const float*)d_in[1];
    const float* head_w = (const float*)d_in[2];
    const float* head_b = (const float*)d_in[3];
    float* out = (float*)d_out;
    int B = in_sizes[0] / NQ;

    hipLaunchKernelGGL(qsim_kernel, dim3(GRID), dim3(NTH), 0, stream,
                       x, params, head_w, head_b, out, B);
}